// Round 4
// baseline (1004.938 us; speedup 1.0000x reference)
//
#include <hip/hip_runtime.h>

#define NYTOT 16384
#define NXP 4096
#define MTOT 65536   // B * NY
#define CYC 128
#define CXC 256
#define DIMC 384

typedef __attribute__((ext_vector_type(8))) _Float16 half8;
typedef __attribute__((ext_vector_type(4))) _Float16 half4;
typedef __attribute__((ext_vector_type(4))) float floatx4;

using half_t = _Float16;

struct alignas(16) HF8 { half_t h[8]; };

// ---------------- K1: 3-NN interpolation + concat -> A0 fp16 [M, 384] ----
// Distances mirror the numpy reference BIT-EXACTLY: fp32, no FMA contraction,
// left-assoc sums, expansion form d = (sy + sx) - 2*inner. Selection is a
// stable strict-< 3-min insertion (lower index wins ties), matching top_k.
__global__ __launch_bounds__(256) void interp_kernel(
    const float* __restrict__ y_points, const float* __restrict__ y_feats,
    const float* __restrict__ x_points, const float* __restrict__ x_feats,
    half_t* __restrict__ A0) {
#pragma clang fp contract(off)
  __shared__ float4 lp[NXP];                         // {x, y, z, sx}  64 KB
  __shared__ int si0[256], si1[256], si2[256];
  __shared__ float sw0[256], sw1[256], sw2[256];
  const int b = blockIdx.x >> 6;
  const int chunk = blockIdx.x & 63;
  const int t = threadIdx.x;

  // stage x_points + per-point sum-of-squares (ref order: (x0*x0+x1*x1)+x2*x2)
  const float* xp = x_points + (size_t)b * NXP * 3;
  for (int j = t; j < NXP; j += 256) {
    float x0 = xp[3 * j], x1 = xp[3 * j + 1], x2 = xp[3 * j + 2];
    float sx = (x0 * x0 + x1 * x1) + x2 * x2;
    float4 v; v.x = x0; v.y = x1; v.z = x2; v.w = sx;
    lp[j] = v;
  }
  __syncthreads();

  const int n = chunk * 256 + t;
  const float* yp = y_points + ((size_t)b * NYTOT + n) * 3;
  float y0 = yp[0], y1 = yp[1], y2 = yp[2];
  float sy = (y0 * y0 + y1 * y1) + y2 * y2;

  float d0 = 1e30f, d1 = 1e30f, d2 = 1e30f;
  int i0 = 0, i1 = 0, i2 = 0;
  for (int j = 0; j < NXP; ++j) {
    float4 p = lp[j];
    float inner = (y0 * p.x + y1 * p.y) + y2 * p.z;   // ref einsum order, no FMA
    float d = (sy + p.w) - 2.0f * inner;              // ref expression tree
    if (d < d2) {               // strict < : stable (lower index wins ties)
      if (d < d1) {
        d2 = d1; i2 = i1;
        if (d < d0) { d1 = d0; i1 = i0; d0 = d; i0 = j; }
        else { d1 = d; i1 = j; }
      } else { d2 = d; i2 = j; }
    }
  }
  // weights in fp32, mirroring ref op order (continuous — rounding immaterial)
  float w0 = 1.0f / (d0 + 1e-8f), w1 = 1.0f / (d1 + 1e-8f), w2 = 1.0f / (d2 + 1e-8f);
  float wsum = (w0 + w1) + w2;
  si0[t] = i0; si1[t] = i1; si2[t] = i2;
  sw0[t] = w0 / wsum; sw1[t] = w1 / wsum; sw2[t] = w2 / wsum;
  __syncthreads();

  // cooperative gather: thread t = channel t, loop over the block's 256 points
  const float* xf = x_feats + (size_t)b * NXP * CXC;
  const float* yfb = y_feats + ((size_t)b * NYTOT + chunk * 256) * CYC;
  half_t* fb = A0 + ((size_t)b * NYTOT + chunk * 256) * DIMC;
  for (int yy = 0; yy < 256; ++yy) {
    int j0 = si0[yy], j1 = si1[yy], j2 = si2[yy];
    float a0 = sw0[yy], a1 = sw1[yy], a2 = sw2[yy];
    float v = (xf[(size_t)j0 * CXC + t] * a0
             + xf[(size_t)j1 * CXC + t] * a1)
             + xf[(size_t)j2 * CXC + t] * a2;
    half_t* row = fb + (size_t)yy * DIMC;
    row[CYC + t] = (half_t)v;
    if (t < CYC) row[t] = (half_t)yfb[(size_t)yy * CYC + t];
  }
}

// ---------------- GEMM: C[M,O] = A[M,K](fp16) * W[O,K](fp32)^T + bias ----
// 128x128 tile, BK=64, 4 waves (2x2), mfma_f32_16x16x32_f16.
// A staged via global_load_lds (16B); W converted fp32->fp16 via VGPR+ds_write.
template<int K, int O>
__global__ __launch_bounds__(256) void gemm_f16(
    const half_t* __restrict__ A, const float* __restrict__ W,
    const float* __restrict__ bias, half_t* __restrict__ C) {
  __shared__ __align__(16) short As[8][2][512];   // [m_sub][k_sub][lane*8+e]
  __shared__ __align__(16) short Bs[8][2][512];
  const int m0 = blockIdx.x * 128;
  const int n0 = blockIdx.y * 128;
  const int tid = threadIdx.x;
  const int lane = tid & 63;
  const int wid = tid >> 6;
  const int wm = wid >> 1, wn = wid & 1;
  const int lm = lane & 15;            // row within 16-subtile
  const int lk = (lane >> 4) * 8;      // k offset within 32
  const int r = tid & 127;             // W-staging: n-row within tile
  const int hh = tid >> 7;             // W-staging: k-half selector
  floatx4 acc[4][4] = {};

  for (int k0 = 0; k0 < K; k0 += 64) {
    __syncthreads();
    // A: 16 chunks of 1 KB via async global->LDS (A already fp16)
#pragma unroll
    for (int c = 0; c < 4; ++c) {
      int id = wid * 4 + c;            // 0..15
      int sub = id >> 1;
      int ks = id & 1;
      const half_t* src = A + (size_t)(m0 + sub * 16 + lm) * K + (k0 + ks * 32 + lk);
      __builtin_amdgcn_global_load_lds(
          (const __attribute__((address_space(1))) void*)src,
          (__attribute__((address_space(3))) void*)&As[sub][ks][0], 16, 0, 0);
    }
    // W: fp32 -> fp16 convert-staging into fragment-ordered LDS
#pragma unroll
    for (int ks = 0; ks < 2; ++ks) {
#pragma unroll
      for (int g = 0; g < 4; ++g) {
        int kw = hh * 16 + g * 4;
        const floatx4 wv = *(const floatx4*)&W[(size_t)(n0 + r) * K + k0 + ks * 32 + kw];
        half4 hv;
        hv[0] = (half_t)wv[0]; hv[1] = (half_t)wv[1];
        hv[2] = (half_t)wv[2]; hv[3] = (half_t)wv[3];
        *(half4*)&Bs[r >> 4][ks][((kw >> 3) * 16 + (r & 15)) * 8 + (kw & 7)] = hv;
      }
    }
    __syncthreads();
#pragma unroll
    for (int ks = 0; ks < 2; ++ks) {
      half8 af[4], bfm[4];
#pragma unroll
      for (int i = 0; i < 4; ++i) af[i] = *(const half8*)&As[wm * 4 + i][ks][lane * 8];
#pragma unroll
      for (int j = 0; j < 4; ++j) bfm[j] = *(const half8*)&Bs[wn * 4 + j][ks][lane * 8];
#pragma unroll
      for (int i = 0; i < 4; ++i)
#pragma unroll
        for (int j = 0; j < 4; ++j)
          acc[i][j] = __builtin_amdgcn_mfma_f32_16x16x32_f16(af[i], bfm[j], acc[i][j], 0, 0, 0);
    }
  }

  // epilogue: C/D layout col=lane&15, row=(lane>>4)*4+r
#pragma unroll
  for (int j = 0; j < 4; ++j) {
    int nn = n0 + wn * 64 + j * 16 + lm;
    float bv = bias[nn];
#pragma unroll
    for (int i = 0; i < 4; ++i) {
      int mr = m0 + wm * 64 + i * 16 + (lane >> 4) * 4;
#pragma unroll
      for (int rr = 0; rr < 4; ++rr)
        C[(size_t)(mr + rr) * O + nn] = (half_t)(acc[i][j][rr] + bv);
    }
  }
}

// ---------------- per-channel sum / sumsq ----------------
__global__ __launch_bounds__(256) void stats_kernel(
    const half_t* __restrict__ Z, float* __restrict__ sums, int O) {
  int c = blockIdx.y * 256 + threadIdx.x;
  if (c >= O) return;
  size_t base = (size_t)blockIdx.x * 512 * O + c;
  float s = 0.f, q = 0.f;
  for (int rr = 0; rr < 512; ++rr) {
    float v = (float)Z[base + (size_t)rr * O];
    s += v; q += v * v;
  }
  atomicAdd(&sums[c], s);
  atomicAdd(&sums[O + c], q);
}

// ---------------- finalize BN scale/shift (with NaN sanitizer) ----------
__global__ void finalize_kernel(const float* __restrict__ sums, const float* __restrict__ g,
                                const float* __restrict__ be, float* __restrict__ ss, int O) {
  int c = threadIdx.x;
  if (c < O) {
    const float invN = 1.0f / 65536.0f;
    float mean = sums[c] * invN;
    float var = sums[O + c] * invN - mean * mean;
    float sc = g[c] / sqrtf(var + 1e-5f);
    float sh = be[c] - mean * sc;
    if (!isfinite(sc) || !isfinite(sh)) { sc = 1.0f; sh = 0.0f; }
    ss[c] = sc;
    ss[O + c] = sh;
  }
}

// ---------------- in-place BN + ReLU (O is power of two) ----------------
__global__ __launch_bounds__(256) void bnrelu_kernel(
    half_t* __restrict__ Z, const float* __restrict__ ss, int O) {
  size_t i = (size_t)blockIdx.x * 256 + threadIdx.x;
  int c0 = (int)((i * 8) & (size_t)(O - 1));
  HF8 v = ((const HF8*)Z)[i];
#pragma unroll
  for (int e = 0; e < 8; ++e) {
    int cc = c0 + e;
    float f = fmaxf((float)v.h[e] * ss[cc] + ss[O + cc], 0.f);
    v.h[e] = (half_t)f;
  }
  ((HF8*)Z)[i] = v;
}

// ---------------- layer3 BN + ReLU + transpose to [B, C, N] fp32 --------
__global__ __launch_bounds__(256) void bn_transpose_kernel(
    const half_t* __restrict__ Z3, const float* __restrict__ ss, float* __restrict__ out) {
  __shared__ float tile[64][129];
  const int r0 = blockIdx.x * 64;
  const int b = r0 >> 14;
  const int n0 = r0 & (NYTOT - 1);
  const int t = threadIdx.x;
  const int cl = t & 127, rl = t >> 7;      // 2 rows per pass
  for (int p = 0; p < 32; ++p) {
    int rr = p * 2 + rl;
    float v = (float)Z3[(size_t)(r0 + rr) * 128 + cl];
    tile[rr][cl] = fmaxf(v * ss[cl] + ss[128 + cl], 0.f);
  }
  __syncthreads();
  const int nl = t & 63, cj = t >> 6;       // 4 channels per pass
  for (int p = 0; p < 32; ++p) {
    int c = p * 4 + cj;
    out[(size_t)b * 128 * NYTOT + (size_t)c * NYTOT + n0 + nl] = tile[nl][c];
  }
}

extern "C" void kernel_launch(void* const* d_in, const int* in_sizes, int n_in,
                              void* d_out, int out_size, void* d_ws, size_t ws_size,
                              hipStream_t stream) {
  const float* y_points = (const float*)d_in[0];
  const float* y_feats  = (const float*)d_in[1];
  const float* x_points = (const float*)d_in[2];
  const float* x_feats  = (const float*)d_in[3];
  const float* W1 = (const float*)d_in[4];  const float* b1 = (const float*)d_in[5];
  const float* g1 = (const float*)d_in[6];  const float* be1 = (const float*)d_in[7];
  const float* W2 = (const float*)d_in[8];  const float* b2 = (const float*)d_in[9];
  const float* g2 = (const float*)d_in[10]; const float* be2 = (const float*)d_in[11];
  const float* W3 = (const float*)d_in[12]; const float* b3 = (const float*)d_in[13];
  const float* g3 = (const float*)d_in[14]; const float* be3 = (const float*)d_in[15];

  // workspace layout (peak 117,454,848 B):
  //   [0, 50.33MB)        : A0 fp16 [M,384]  (later aliased by z2)
  //   [50.33MB, 117.44MB) : z1 fp16 [M,512]  (later aliased by z3)
  //   [117.44MB, +14KB)   : BN stats
  char* ws = (char*)d_ws;
  half_t* A0 = (half_t*)ws;                      // 65536*384*2 = 50,331,648
  half_t* z1 = (half_t*)(ws + 50331648);         // 65536*512*2 = 67,108,864
  half_t* z2 = (half_t*)ws;                      // alias A0 (dead after gemm1)
  half_t* z3 = (half_t*)(ws + 50331648);         // alias z1 (dead after gemm2)
  float* st = (float*)(ws + 117440512);
  // st floats: sum1/sq1 @0 (1024), sum2/sq2 @1024 (512), sum3/sq3 @1536 (256),
  //            ss1 @1792 (1024), ss2 @2816 (512), ss3 @3328 (256)
  hipMemsetAsync(st, 0, 1792 * sizeof(float), stream);

  interp_kernel<<<256, 256, 0, stream>>>(y_points, y_feats, x_points, x_feats, A0);

  gemm_f16<384, 512><<<dim3(512, 4), 256, 0, stream>>>(A0, W1, b1, z1);
  stats_kernel<<<dim3(128, 2), 256, 0, stream>>>(z1, st + 0, 512);
  finalize_kernel<<<1, 512, 0, stream>>>(st + 0, g1, be1, st + 1792, 512);
  bnrelu_kernel<<<16384, 256, 0, stream>>>(z1, st + 1792, 512);

  gemm_f16<512, 256><<<dim3(512, 2), 256, 0, stream>>>(z1, W2, b2, z2);
  stats_kernel<<<dim3(128, 1), 256, 0, stream>>>(z2, st + 1024, 256);
  finalize_kernel<<<1, 256, 0, stream>>>(st + 1024, g2, be2, st + 2816, 256);
  bnrelu_kernel<<<8192, 256, 0, stream>>>(z2, st + 2816, 256);

  gemm_f16<256, 128><<<dim3(512, 1), 256, 0, stream>>>(z2, W3, b3, z3);
  stats_kernel<<<dim3(128, 1), 256, 0, stream>>>(z3, st + 1536, 128);
  finalize_kernel<<<1, 128, 0, stream>>>(st + 1536, g3, be3, st + 3328, 128);

  bn_transpose_kernel<<<1024, 256, 0, stream>>>(z3, st + 3328, (float*)d_out);
}

// Round 5
// 632.022 us; speedup vs baseline: 1.5900x; 1.5900x over previous
//
#include <hip/hip_runtime.h>

#define NYTOT 16384
#define NXP 4096
#define MTOT 65536   // B * NY
#define CYC 128
#define CXC 256
#define DIMC 384

typedef __attribute__((ext_vector_type(8))) _Float16 half8;
typedef __attribute__((ext_vector_type(4))) _Float16 half4;
typedef __attribute__((ext_vector_type(4))) float floatx4;

using half_t = _Float16;

struct alignas(16) HF8 { half_t h[8]; };

// ---------------- K1: 3-NN interpolation + concat -> A0 fp16 [M, 384] ----
// Distances mirror the numpy reference BIT-EXACTLY: fp32, no FMA contraction,
// left-assoc sums, d = (sy + sx) - 2*inner. Branchless strict-< top-3
// (cndmask chain). X-scan split across 4 segments (4 waves per y-chunk);
// segment partials merged in seg order -> identical stable tie-breaking
// (segments are index-disjoint ascending ranges).
__global__ __launch_bounds__(1024, 4) void interp_kernel(
    const float* __restrict__ y_points, const float* __restrict__ y_feats,
    const float* __restrict__ x_points, const float* __restrict__ x_feats,
    half_t* __restrict__ A0) {
#pragma clang fp contract(off)
  __shared__ float4 lp[NXP];              // {x, y, z, sx}  64 KB
  __shared__ float pd[4][256][3];         // 12 KB partial dists
  __shared__ int   pi[4][256][3];         // 12 KB partial idx
  __shared__ float sw[3][256];            // 3 KB final weights
  __shared__ int   si[3][256];            // 3 KB final idx
  const int b = blockIdx.x >> 6;
  const int chunk = blockIdx.x & 63;
  const int t = threadIdx.x;

  // stage x_points + per-point sum-of-squares (ref order)
  const float* xp = x_points + (size_t)b * NXP * 3;
  for (int j = t; j < NXP; j += 1024) {
    float x0 = xp[3 * j], x1 = xp[3 * j + 1], x2 = xp[3 * j + 2];
    float sx = (x0 * x0 + x1 * x1) + x2 * x2;
    float4 v; v.x = x0; v.y = x1; v.z = x2; v.w = sx;
    lp[j] = v;
  }
  __syncthreads();

  const int seg = t >> 8, yy = t & 255;
  const int n = chunk * 256 + yy;
  const float* yp = y_points + ((size_t)b * NYTOT + n) * 3;
  float y0 = yp[0], y1 = yp[1], y2 = yp[2];
  float sy = (y0 * y0 + y1 * y1) + y2 * y2;

  float d0 = 1e30f, d1 = 1e30f, d2 = 1e30f;
  int i0 = 0, i1 = 0, i2 = 0;
  const int jbase = seg * 1024;
#pragma unroll 4
  for (int jj = 0; jj < 1024; ++jj) {
    int j = jbase + jj;
    float4 p = lp[j];
    float inner = (y0 * p.x + y1 * p.y) + y2 * p.z;   // ref einsum order, no FMA
    float d = (sy + p.w) - 2.0f * inner;              // ref expression tree
    bool lt0 = d < d0, lt1 = d < d1, lt2 = d < d2;    // strict <: stable
    d2 = lt1 ? d1 : (lt2 ? d : d2);  i2 = lt1 ? i1 : (lt2 ? j : i2);
    d1 = lt0 ? d0 : (lt1 ? d : d1);  i1 = lt0 ? i0 : (lt1 ? j : i1);
    d0 = lt0 ? d  : d0;              i0 = lt0 ? j  : i0;
  }
  pd[seg][yy][0] = d0; pd[seg][yy][1] = d1; pd[seg][yy][2] = d2;
  pi[seg][yy][0] = i0; pi[seg][yy][1] = i1; pi[seg][yy][2] = i2;
  __syncthreads();

  // merge 4 partial top-3 lists (seg order preserves lowest-index-wins ties)
  if (t < 256) {
    float e0 = 1e30f, e1 = 1e30f, e2 = 1e30f;
    int k0 = 0, k1 = 0, k2 = 0;
#pragma unroll
    for (int s = 0; s < 4; ++s)
#pragma unroll
      for (int c = 0; c < 3; ++c) {
        float d = pd[s][t][c]; int j = pi[s][t][c];
        bool lt0 = d < e0, lt1 = d < e1, lt2 = d < e2;
        e2 = lt1 ? e1 : (lt2 ? d : e2);  k2 = lt1 ? k1 : (lt2 ? j : k2);
        e1 = lt0 ? e0 : (lt1 ? d : e1);  k1 = lt0 ? k0 : (lt1 ? j : k1);
        e0 = lt0 ? d  : e0;              k0 = lt0 ? j  : k0;
      }
    float w0 = 1.0f / (e0 + 1e-8f), w1 = 1.0f / (e1 + 1e-8f), w2 = 1.0f / (e2 + 1e-8f);
    float ws = (w0 + w1) + w2;
    sw[0][t] = w0 / ws; sw[1][t] = w1 / ws; sw[2][t] = w2 / ws;
    si[0][t] = k0; si[1][t] = k1; si[2][t] = k2;
  }
  __syncthreads();

  // gather: thread = (y-sub, channel); 4 y rows in flight
  const float* xf = x_feats + (size_t)b * NXP * CXC;
  const float* yfb = y_feats + ((size_t)b * NYTOT + chunk * 256) * CYC;
  half_t* fb = A0 + ((size_t)b * NYTOT + chunk * 256) * DIMC;
  const int c = t & 255, ysub = t >> 8;
  for (int y2 = ysub; y2 < 256; y2 += 4) {
    int j0 = si[0][y2], j1 = si[1][y2], j2 = si[2][y2];
    float a0 = sw[0][y2], a1 = sw[1][y2], a2 = sw[2][y2];
    float v = (xf[(size_t)j0 * CXC + c] * a0
             + xf[(size_t)j1 * CXC + c] * a1)
             + xf[(size_t)j2 * CXC + c] * a2;
    half_t* row = fb + (size_t)y2 * DIMC;
    row[CYC + c] = (half_t)v;
    if (c < CYC) row[c] = (half_t)yfb[(size_t)y2 * CYC + c];
  }
}

// ---------------- GEMM: C[M,O] = A[M,K](fp16) * W[O,K](fp32)^T + bias ----
// 128x128 tile, BK=64, 4 waves (2x2), mfma_f32_16x16x32_f16.
// A staged via global_load_lds (16B); W converted fp32->fp16 via VGPR+ds_write.
// Fused BN stats: per-channel sum/sumsq of z reduced in-wave, atomicAdd.
template<int K, int O>
__global__ __launch_bounds__(256) void gemm_f16(
    const half_t* __restrict__ A, const float* __restrict__ W,
    const float* __restrict__ bias, half_t* __restrict__ C,
    float* __restrict__ sums) {
  __shared__ __align__(16) short As[8][2][512];   // [m_sub][k_sub][lane*8+e]
  __shared__ __align__(16) short Bs[8][2][512];
  const int m0 = blockIdx.x * 128;
  const int n0 = blockIdx.y * 128;
  const int tid = threadIdx.x;
  const int lane = tid & 63;
  const int wid = tid >> 6;
  const int wm = wid >> 1, wn = wid & 1;
  const int lm = lane & 15;            // row within 16-subtile
  const int lk = (lane >> 4) * 8;      // k offset within 32
  const int r = tid & 127;             // W-staging: n-row within tile
  const int hh = tid >> 7;             // W-staging: k-half selector
  floatx4 acc[4][4] = {};

  for (int k0 = 0; k0 < K; k0 += 64) {
    __syncthreads();
    // A: 16 chunks of 1 KB via async global->LDS (A already fp16)
#pragma unroll
    for (int c = 0; c < 4; ++c) {
      int id = wid * 4 + c;            // 0..15
      int sub = id >> 1;
      int ks = id & 1;
      const half_t* src = A + (size_t)(m0 + sub * 16 + lm) * K + (k0 + ks * 32 + lk);
      __builtin_amdgcn_global_load_lds(
          (const __attribute__((address_space(1))) void*)src,
          (__attribute__((address_space(3))) void*)&As[sub][ks][0], 16, 0, 0);
    }
    // W: fp32 -> fp16 convert-staging into fragment-ordered LDS
#pragma unroll
    for (int ks = 0; ks < 2; ++ks) {
#pragma unroll
      for (int g = 0; g < 4; ++g) {
        int kw = hh * 16 + g * 4;
        const floatx4 wv = *(const floatx4*)&W[(size_t)(n0 + r) * K + k0 + ks * 32 + kw];
        half4 hv;
        hv[0] = (half_t)wv[0]; hv[1] = (half_t)wv[1];
        hv[2] = (half_t)wv[2]; hv[3] = (half_t)wv[3];
        *(half4*)&Bs[r >> 4][ks][((kw >> 3) * 16 + (r & 15)) * 8 + (kw & 7)] = hv;
      }
    }
    __syncthreads();
#pragma unroll
    for (int ks = 0; ks < 2; ++ks) {
      half8 af[4], bfm[4];
#pragma unroll
      for (int i = 0; i < 4; ++i) af[i] = *(const half8*)&As[wm * 4 + i][ks][lane * 8];
#pragma unroll
      for (int j = 0; j < 4; ++j) bfm[j] = *(const half8*)&Bs[wn * 4 + j][ks][lane * 8];
#pragma unroll
      for (int i = 0; i < 4; ++i)
#pragma unroll
        for (int j = 0; j < 4; ++j)
          acc[i][j] = __builtin_amdgcn_mfma_f32_16x16x32_f16(af[i], bfm[j], acc[i][j], 0, 0, 0);
    }
  }

  // epilogue: C/D layout col=lane&15, row=(lane>>4)*4+r; fused BN stats
#pragma unroll
  for (int j = 0; j < 4; ++j) {
    int nn = n0 + wn * 64 + j * 16 + lm;
    float bv = bias[nn];
    float psum = 0.f, psq = 0.f;
#pragma unroll
    for (int i = 0; i < 4; ++i) {
      int mr = m0 + wm * 64 + i * 16 + (lane >> 4) * 4;
#pragma unroll
      for (int rr = 0; rr < 4; ++rr) {
        float z = acc[i][j][rr] + bv;
        C[(size_t)(mr + rr) * O + nn] = (half_t)z;
        psum += z; psq += z * z;
      }
    }
    // reduce the 4 lane-groups holding channel nn (lanes lm, lm+16, lm+32, lm+48)
    psum += __shfl_xor(psum, 16, 64); psq += __shfl_xor(psq, 16, 64);
    psum += __shfl_xor(psum, 32, 64); psq += __shfl_xor(psq, 32, 64);
    if ((lane >> 4) == 0) {
      atomicAdd(&sums[nn], psum);
      atomicAdd(&sums[O + nn], psq);
    }
  }
}

// ---------------- finalize BN scale/shift ----------
__global__ void finalize_kernel(const float* __restrict__ sums, const float* __restrict__ g,
                                const float* __restrict__ be, float* __restrict__ ss, int O) {
  int c = threadIdx.x;
  if (c < O) {
    const float invN = 1.0f / 65536.0f;
    float mean = sums[c] * invN;
    float var = sums[O + c] * invN - mean * mean;
    float sc = g[c] / sqrtf(var + 1e-5f);
    float sh = be[c] - mean * sc;
    if (!isfinite(sc) || !isfinite(sh)) { sc = 1.0f; sh = 0.0f; }
    ss[c] = sc;
    ss[O + c] = sh;
  }
}

// ---------------- in-place BN + ReLU (O is power of two) ----------------
__global__ __launch_bounds__(256) void bnrelu_kernel(
    half_t* __restrict__ Z, const float* __restrict__ ss, int O) {
  size_t i = (size_t)blockIdx.x * 256 + threadIdx.x;
  int c0 = (int)((i * 8) & (size_t)(O - 1));
  HF8 v = ((const HF8*)Z)[i];
#pragma unroll
  for (int e = 0; e < 8; ++e) {
    int cc = c0 + e;
    float f = fmaxf((float)v.h[e] * ss[cc] + ss[O + cc], 0.f);
    v.h[e] = (half_t)f;
  }
  ((HF8*)Z)[i] = v;
}

// ---------------- layer3 BN + ReLU + transpose to [B, C, N] fp32 --------
__global__ __launch_bounds__(256) void bn_transpose_kernel(
    const half_t* __restrict__ Z3, const float* __restrict__ ss, float* __restrict__ out) {
  __shared__ float tile[64][129];
  const int r0 = blockIdx.x * 64;
  const int b = r0 >> 14;
  const int n0 = r0 & (NYTOT - 1);
  const int t = threadIdx.x;
  const int cl = t & 127, rl = t >> 7;      // 2 rows per pass
  for (int p = 0; p < 32; ++p) {
    int rr = p * 2 + rl;
    float v = (float)Z3[(size_t)(r0 + rr) * 128 + cl];
    tile[rr][cl] = fmaxf(v * ss[cl] + ss[128 + cl], 0.f);
  }
  __syncthreads();
  const int nl = t & 63, cj = t >> 6;       // 4 channels per pass
  for (int p = 0; p < 32; ++p) {
    int c = p * 4 + cj;
    out[(size_t)b * 128 * NYTOT + (size_t)c * NYTOT + n0 + nl] = tile[nl][c];
  }
}

extern "C" void kernel_launch(void* const* d_in, const int* in_sizes, int n_in,
                              void* d_out, int out_size, void* d_ws, size_t ws_size,
                              hipStream_t stream) {
  const float* y_points = (const float*)d_in[0];
  const float* y_feats  = (const float*)d_in[1];
  const float* x_points = (const float*)d_in[2];
  const float* x_feats  = (const float*)d_in[3];
  const float* W1 = (const float*)d_in[4];  const float* b1 = (const float*)d_in[5];
  const float* g1 = (const float*)d_in[6];  const float* be1 = (const float*)d_in[7];
  const float* W2 = (const float*)d_in[8];  const float* b2 = (const float*)d_in[9];
  const float* g2 = (const float*)d_in[10]; const float* be2 = (const float*)d_in[11];
  const float* W3 = (const float*)d_in[12]; const float* b3 = (const float*)d_in[13];
  const float* g3 = (const float*)d_in[14]; const float* be3 = (const float*)d_in[15];

  // workspace layout (peak 117,454,848 B):
  //   [0, 50.33MB)        : A0 fp16 [M,384]  (later aliased by z2)
  //   [50.33MB, 117.44MB) : z1 fp16 [M,512]  (later aliased by z3)
  //   [117.44MB, +14KB)   : BN stats
  char* ws = (char*)d_ws;
  half_t* A0 = (half_t*)ws;                      // 65536*384*2 = 50,331,648
  half_t* z1 = (half_t*)(ws + 50331648);         // 65536*512*2 = 67,108,864
  half_t* z2 = (half_t*)ws;                      // alias A0 (dead after gemm1)
  half_t* z3 = (half_t*)(ws + 50331648);         // alias z1 (dead after gemm2)
  float* st = (float*)(ws + 117440512);
  // st floats: sum1/sq1 @0 (1024), sum2/sq2 @1024 (512), sum3/sq3 @1536 (256),
  //            ss1 @1792 (1024), ss2 @2816 (512), ss3 @3328 (256)
  hipMemsetAsync(st, 0, 1792 * sizeof(float), stream);

  interp_kernel<<<256, 1024, 0, stream>>>(y_points, y_feats, x_points, x_feats, A0);

  gemm_f16<384, 512><<<dim3(512, 4), 256, 0, stream>>>(A0, W1, b1, z1, st + 0);
  finalize_kernel<<<1, 512, 0, stream>>>(st + 0, g1, be1, st + 1792, 512);
  bnrelu_kernel<<<16384, 256, 0, stream>>>(z1, st + 1792, 512);

  gemm_f16<512, 256><<<dim3(512, 2), 256, 0, stream>>>(z1, W2, b2, z2, st + 1024);
  finalize_kernel<<<1, 256, 0, stream>>>(st + 1024, g2, be2, st + 2816, 256);
  bnrelu_kernel<<<8192, 256, 0, stream>>>(z2, st + 2816, 256);

  gemm_f16<256, 128><<<dim3(512, 1), 256, 0, stream>>>(z2, W3, b3, z3, st + 1536);
  finalize_kernel<<<1, 128, 0, stream>>>(st + 1536, g3, be3, st + 3328, 128);

  bn_transpose_kernel<<<1024, 256, 0, stream>>>(z3, st + 3328, (float*)d_out);
}

// Round 6
// 615.610 us; speedup vs baseline: 1.6324x; 1.0267x over previous
//
#include <hip/hip_runtime.h>

#define NYTOT 16384
#define NXP 4096
#define MTOT 65536   // B * NY
#define CYC 128
#define CXC 256
#define DIMC 384

typedef __attribute__((ext_vector_type(8))) _Float16 half8;
typedef __attribute__((ext_vector_type(4))) _Float16 half4;
typedef __attribute__((ext_vector_type(4))) float floatx4;

using half_t = _Float16;

struct alignas(16) HF8 { half_t h[8]; };

// ---------------- K1: 3-NN interpolation + concat -> A0 fp16 [M, 384] ----
// Distances mirror the numpy reference BIT-EXACTLY: fp32, no FMA contraction,
// left-assoc sums, d = (sy + sx) - 2*inner.
// Phase 1: value-only top-3 via min/med3 (3 select ops, bit-exact selection).
// Phase 2: sparse index recovery — full stable insertion only where d <= t2
// (t2 = global 3rd-smallest), ~0.1% of lane-iters. Merge in segment order
// preserves lowest-index-wins ties exactly (segments are ascending j ranges).
__global__ __launch_bounds__(1024, 4) void interp_kernel(
    const float* __restrict__ y_points, const float* __restrict__ y_feats,
    const float* __restrict__ x_points, const float* __restrict__ x_feats,
    half_t* __restrict__ A0) {
#pragma clang fp contract(off)
  __shared__ float4 lp[NXP];              // {x, y, z, sx}  64 KB
  __shared__ float pd[4][256][3];         // 12 KB partial dists
  __shared__ int   pi[4][256][3];         // 12 KB partial idx
  __shared__ float sw[3][256];            // 3 KB final weights
  __shared__ int   si[3][256];            // 3 KB final idx
  const int b = blockIdx.x >> 6;
  const int chunk = blockIdx.x & 63;
  const int t = threadIdx.x;

  // stage x_points + per-point sum-of-squares (ref order)
  const float* xp = x_points + (size_t)b * NXP * 3;
  for (int j = t; j < NXP; j += 1024) {
    float x0 = xp[3 * j], x1 = xp[3 * j + 1], x2 = xp[3 * j + 2];
    float sx = (x0 * x0 + x1 * x1) + x2 * x2;
    float4 v; v.x = x0; v.y = x1; v.z = x2; v.w = sx;
    lp[j] = v;
  }
  __syncthreads();

  const int seg = t >> 8, yy = t & 255;
  const int n = chunk * 256 + yy;
  const float* yp = y_points + ((size_t)b * NYTOT + n) * 3;
  float y0 = yp[0], y1 = yp[1], y2 = yp[2];
  float sy = (y0 * y0 + y1 * y1) + y2 * y2;
  const int jbase = seg * 1024;

  // ---- phase 1: value-only top-3 (min/med3 — 3 select ops/candidate) ----
  float d0 = 1e30f, d1 = 1e30f, d2 = 1e30f;
#pragma unroll 8
  for (int jj = 0; jj < 1024; ++jj) {
    float4 p = lp[jbase + jj];
    float inner = (y0 * p.x + y1 * p.y) + y2 * p.z;   // ref einsum order, no FMA
    float d = (sy + p.w) - 2.0f * inner;              // ref expression tree
    d2 = __builtin_amdgcn_fmed3f(d, d1, d2);          // new 3rd  (old d1,d2)
    d1 = __builtin_amdgcn_fmed3f(d, d0, d1);          // new 2nd  (old d0,d1)
    d0 = fminf(d, d0);                                // new 1st
  }
  pd[seg][yy][0] = d0; pd[seg][yy][1] = d1; pd[seg][yy][2] = d2;
  __syncthreads();

  // global 3rd-smallest value t2 (each of the 4 seg-threads computes it)
  float t2;
  {
    float m0 = 1e30f, m1 = 1e30f, m2 = 1e30f;
#pragma unroll
    for (int s = 0; s < 4; ++s)
#pragma unroll
      for (int c = 0; c < 3; ++c) {
        float v = pd[s][yy][c];
        m2 = __builtin_amdgcn_fmed3f(v, m1, m2);
        m1 = __builtin_amdgcn_fmed3f(v, m0, m1);
        m0 = fminf(v, m0);
      }
    t2 = m2;
  }
  __syncthreads();   // protect pd before phase-2 overwrite

  // ---- phase 2: sparse index recovery (stable insertion, rarely taken) ----
  float e0 = 1e30f, e1 = 1e30f, e2 = 1e30f;
  int k0 = 0, k1 = 0, k2 = 0;
#pragma unroll 4
  for (int jj = 0; jj < 1024; ++jj) {
    int j = jbase + jj;
    float4 p = lp[j];
    float inner = (y0 * p.x + y1 * p.y) + y2 * p.z;
    float d = (sy + p.w) - 2.0f * inner;
    if (d <= t2) {                       // wave skips via execz ~91% of iters
      bool lt0 = d < e0, lt1 = d < e1, lt2 = d < e2;   // strict <: stable
      e2 = lt1 ? e1 : (lt2 ? d : e2);  k2 = lt1 ? k1 : (lt2 ? j : k2);
      e1 = lt0 ? e0 : (lt1 ? d : e1);  k1 = lt0 ? k0 : (lt1 ? j : k1);
      e0 = lt0 ? d  : e0;              k0 = lt0 ? j  : k0;
    }
  }
  pd[seg][yy][0] = e0; pd[seg][yy][1] = e1; pd[seg][yy][2] = e2;
  pi[seg][yy][0] = k0; pi[seg][yy][1] = k1; pi[seg][yy][2] = k2;
  __syncthreads();

  // merge 4 partial top-3 lists (seg order preserves lowest-index-wins ties)
  if (t < 256) {
    float f0 = 1e30f, f1 = 1e30f, f2 = 1e30f;
    int m0i = 0, m1i = 0, m2i = 0;
#pragma unroll
    for (int s = 0; s < 4; ++s)
#pragma unroll
      for (int c = 0; c < 3; ++c) {
        float d = pd[s][t][c]; int j = pi[s][t][c];
        bool lt0 = d < f0, lt1 = d < f1, lt2 = d < f2;
        f2 = lt1 ? f1 : (lt2 ? d : f2);  m2i = lt1 ? m1i : (lt2 ? j : m2i);
        f1 = lt0 ? f0 : (lt1 ? d : f1);  m1i = lt0 ? m0i : (lt1 ? j : m1i);
        f0 = lt0 ? d  : f0;              m0i = lt0 ? j  : m0i;
      }
    float w0 = 1.0f / (f0 + 1e-8f), w1 = 1.0f / (f1 + 1e-8f), w2 = 1.0f / (f2 + 1e-8f);
    float ws = (w0 + w1) + w2;
    sw[0][t] = w0 / ws; sw[1][t] = w1 / ws; sw[2][t] = w2 / ws;
    si[0][t] = m0i; si[1][t] = m1i; si[2][t] = m2i;
  }
  __syncthreads();

  // ---- gather: vectorized float4 rows (row index wave-uniform -> 1KB loads)
  // weighted sum is continuous math: fmaf allowed (no tie semantics here)
  const floatx4* xf4 = (const floatx4*)(x_feats + (size_t)b * NXP * CXC);
  const floatx4* yf4 = (const floatx4*)(y_feats + ((size_t)b * NYTOT + chunk * 256) * CYC);
  half_t* fb = A0 + ((size_t)b * NYTOT + chunk * 256) * DIMC;
  {
    const int q = t & 63;           // float4 index within 256-ch row
    const int ysub = t >> 6;        // 16 y-groups
    for (int y2 = ysub; y2 < 256; y2 += 16) {
      int j0 = si[0][y2], j1 = si[1][y2], j2 = si[2][y2];
      float a0 = sw[0][y2], a1 = sw[1][y2], a2 = sw[2][y2];
      floatx4 v0 = xf4[(size_t)j0 * 64 + q];
      floatx4 v1 = xf4[(size_t)j1 * 64 + q];
      floatx4 v2 = xf4[(size_t)j2 * 64 + q];
      half4 h;
#pragma unroll
      for (int e = 0; e < 4; ++e)
        h[e] = (half_t)fmaf(v2[e], a2, fmaf(v1[e], a1, v0[e] * a0));
      *(half4*)&fb[(size_t)y2 * DIMC + CYC + q * 4] = h;
    }
  }
  {
    const int q2 = t & 31;          // float4 index within 128-ch row
    const int ysub2 = t >> 5;       // 32 y-groups
    for (int y2 = ysub2; y2 < 256; y2 += 32) {
      floatx4 v = yf4[(size_t)y2 * 32 + q2];
      half4 h;
#pragma unroll
      for (int e = 0; e < 4; ++e) h[e] = (half_t)v[e];
      *(half4*)&fb[(size_t)y2 * DIMC + q2 * 4] = h;
    }
  }
}

// ---------------- GEMM: C[M,O] = A[M,K](fp16) * W[O,K](fp32)^T + bias ----
// 128x128 tile, BK=64, 4 waves (2x2), mfma_f32_16x16x32_f16.
// A staged via global_load_lds (16B); W converted fp32->fp16 via VGPR+ds_write.
// Fused BN stats: per-channel sum/sumsq of z reduced in-wave, atomicAdd.
template<int K, int O>
__global__ __launch_bounds__(256) void gemm_f16(
    const half_t* __restrict__ A, const float* __restrict__ W,
    const float* __restrict__ bias, half_t* __restrict__ C,
    float* __restrict__ sums) {
  __shared__ __align__(16) short As[8][2][512];   // [m_sub][k_sub][lane*8+e]
  __shared__ __align__(16) short Bs[8][2][512];
  const int m0 = blockIdx.x * 128;
  const int n0 = blockIdx.y * 128;
  const int tid = threadIdx.x;
  const int lane = tid & 63;
  const int wid = tid >> 6;
  const int wm = wid >> 1, wn = wid & 1;
  const int lm = lane & 15;            // row within 16-subtile
  const int lk = (lane >> 4) * 8;      // k offset within 32
  const int r = tid & 127;             // W-staging: n-row within tile
  const int hh = tid >> 7;             // W-staging: k-half selector
  floatx4 acc[4][4] = {};

  for (int k0 = 0; k0 < K; k0 += 64) {
    __syncthreads();
    // A: 16 chunks of 1 KB via async global->LDS (A already fp16)
#pragma unroll
    for (int c = 0; c < 4; ++c) {
      int id = wid * 4 + c;            // 0..15
      int sub = id >> 1;
      int ks = id & 1;
      const half_t* src = A + (size_t)(m0 + sub * 16 + lm) * K + (k0 + ks * 32 + lk);
      __builtin_amdgcn_global_load_lds(
          (const __attribute__((address_space(1))) void*)src,
          (__attribute__((address_space(3))) void*)&As[sub][ks][0], 16, 0, 0);
    }
    // W: fp32 -> fp16 convert-staging into fragment-ordered LDS
#pragma unroll
    for (int ks = 0; ks < 2; ++ks) {
#pragma unroll
      for (int g = 0; g < 4; ++g) {
        int kw = hh * 16 + g * 4;
        const floatx4 wv = *(const floatx4*)&W[(size_t)(n0 + r) * K + k0 + ks * 32 + kw];
        half4 hv;
        hv[0] = (half_t)wv[0]; hv[1] = (half_t)wv[1];
        hv[2] = (half_t)wv[2]; hv[3] = (half_t)wv[3];
        *(half4*)&Bs[r >> 4][ks][((kw >> 3) * 16 + (r & 15)) * 8 + (kw & 7)] = hv;
      }
    }
    __syncthreads();
#pragma unroll
    for (int ks = 0; ks < 2; ++ks) {
      half8 af[4], bfm[4];
#pragma unroll
      for (int i = 0; i < 4; ++i) af[i] = *(const half8*)&As[wm * 4 + i][ks][lane * 8];
#pragma unroll
      for (int j = 0; j < 4; ++j) bfm[j] = *(const half8*)&Bs[wn * 4 + j][ks][lane * 8];
#pragma unroll
      for (int i = 0; i < 4; ++i)
#pragma unroll
        for (int j = 0; j < 4; ++j)
          acc[i][j] = __builtin_amdgcn_mfma_f32_16x16x32_f16(af[i], bfm[j], acc[i][j], 0, 0, 0);
    }
  }

  // epilogue: C/D layout col=lane&15, row=(lane>>4)*4+r; fused BN stats
#pragma unroll
  for (int j = 0; j < 4; ++j) {
    int nn = n0 + wn * 64 + j * 16 + lm;
    float bv = bias[nn];
    float psum = 0.f, psq = 0.f;
#pragma unroll
    for (int i = 0; i < 4; ++i) {
      int mr = m0 + wm * 64 + i * 16 + (lane >> 4) * 4;
#pragma unroll
      for (int rr = 0; rr < 4; ++rr) {
        float z = acc[i][j][rr] + bv;
        C[(size_t)(mr + rr) * O + nn] = (half_t)z;
        psum += z; psq += z * z;
      }
    }
    // reduce the 4 lane-groups holding channel nn (lanes lm, lm+16, lm+32, lm+48)
    psum += __shfl_xor(psum, 16, 64); psq += __shfl_xor(psq, 16, 64);
    psum += __shfl_xor(psum, 32, 64); psq += __shfl_xor(psq, 32, 64);
    if ((lane >> 4) == 0) {
      atomicAdd(&sums[nn], psum);
      atomicAdd(&sums[O + nn], psq);
    }
  }
}

// ---------------- finalize BN scale/shift ----------
__global__ void finalize_kernel(const float* __restrict__ sums, const float* __restrict__ g,
                                const float* __restrict__ be, float* __restrict__ ss, int O) {
  int c = threadIdx.x;
  if (c < O) {
    const float invN = 1.0f / 65536.0f;
    float mean = sums[c] * invN;
    float var = sums[O + c] * invN - mean * mean;
    float sc = g[c] / sqrtf(var + 1e-5f);
    float sh = be[c] - mean * sc;
    if (!isfinite(sc) || !isfinite(sh)) { sc = 1.0f; sh = 0.0f; }
    ss[c] = sc;
    ss[O + c] = sh;
  }
}

// ---------------- in-place BN + ReLU (O is power of two) ----------------
__global__ __launch_bounds__(256) void bnrelu_kernel(
    half_t* __restrict__ Z, const float* __restrict__ ss, int O) {
  size_t i = (size_t)blockIdx.x * 256 + threadIdx.x;
  int c0 = (int)((i * 8) & (size_t)(O - 1));
  HF8 v = ((const HF8*)Z)[i];
#pragma unroll
  for (int e = 0; e < 8; ++e) {
    int cc = c0 + e;
    float f = fmaxf((float)v.h[e] * ss[cc] + ss[O + cc], 0.f);
    v.h[e] = (half_t)f;
  }
  ((HF8*)Z)[i] = v;
}

// ---------------- layer3 BN + ReLU + transpose to [B, C, N] fp32 --------
__global__ __launch_bounds__(256) void bn_transpose_kernel(
    const half_t* __restrict__ Z3, const float* __restrict__ ss, float* __restrict__ out) {
  __shared__ float tile[64][129];
  const int r0 = blockIdx.x * 64;
  const int b = r0 >> 14;
  const int n0 = r0 & (NYTOT - 1);
  const int t = threadIdx.x;
  const int cl = t & 127, rl = t >> 7;      // 2 rows per pass
  for (int p = 0; p < 32; ++p) {
    int rr = p * 2 + rl;
    float v = (float)Z3[(size_t)(r0 + rr) * 128 + cl];
    tile[rr][cl] = fmaxf(v * ss[cl] + ss[128 + cl], 0.f);
  }
  __syncthreads();
  const int nl = t & 63, cj = t >> 6;       // 4 channels per pass
  for (int p = 0; p < 32; ++p) {
    int c = p * 4 + cj;
    out[(size_t)b * 128 * NYTOT + (size_t)c * NYTOT + n0 + nl] = tile[nl][c];
  }
}

extern "C" void kernel_launch(void* const* d_in, const int* in_sizes, int n_in,
                              void* d_out, int out_size, void* d_ws, size_t ws_size,
                              hipStream_t stream) {
  const float* y_points = (const float*)d_in[0];
  const float* y_feats  = (const float*)d_in[1];
  const float* x_points = (const float*)d_in[2];
  const float* x_feats  = (const float*)d_in[3];
  const float* W1 = (const float*)d_in[4];  const float* b1 = (const float*)d_in[5];
  const float* g1 = (const float*)d_in[6];  const float* be1 = (const float*)d_in[7];
  const float* W2 = (const float*)d_in[8];  const float* b2 = (const float*)d_in[9];
  const float* g2 = (const float*)d_in[10]; const float* be2 = (const float*)d_in[11];
  const float* W3 = (const float*)d_in[12]; const float* b3 = (const float*)d_in[13];
  const float* g3 = (const float*)d_in[14]; const float* be3 = (const float*)d_in[15];

  // workspace layout (peak 117,454,848 B):
  //   [0, 50.33MB)        : A0 fp16 [M,384]  (later aliased by z2)
  //   [50.33MB, 117.44MB) : z1 fp16 [M,512]  (later aliased by z3)
  //   [117.44MB, +14KB)   : BN stats
  char* ws = (char*)d_ws;
  half_t* A0 = (half_t*)ws;                      // 65536*384*2 = 50,331,648
  half_t* z1 = (half_t*)(ws + 50331648);         // 65536*512*2 = 67,108,864
  half_t* z2 = (half_t*)ws;                      // alias A0 (dead after gemm1)
  half_t* z3 = (half_t*)(ws + 50331648);         // alias z1 (dead after gemm2)
  float* st = (float*)(ws + 117440512);
  // st floats: sum1/sq1 @0 (1024), sum2/sq2 @1024 (512), sum3/sq3 @1536 (256),
  //            ss1 @1792 (1024), ss2 @2816 (512), ss3 @3328 (256)
  hipMemsetAsync(st, 0, 1792 * sizeof(float), stream);

  interp_kernel<<<256, 1024, 0, stream>>>(y_points, y_feats, x_points, x_feats, A0);

  gemm_f16<384, 512><<<dim3(512, 4), 256, 0, stream>>>(A0, W1, b1, z1, st + 0);
  finalize_kernel<<<1, 512, 0, stream>>>(st + 0, g1, be1, st + 1792, 512);
  bnrelu_kernel<<<16384, 256, 0, stream>>>(z1, st + 1792, 512);

  gemm_f16<512, 256><<<dim3(512, 2), 256, 0, stream>>>(z1, W2, b2, z2, st + 1024);
  finalize_kernel<<<1, 256, 0, stream>>>(st + 1024, g2, be2, st + 2816, 256);
  bnrelu_kernel<<<8192, 256, 0, stream>>>(z2, st + 2816, 256);

  gemm_f16<256, 128><<<dim3(512, 1), 256, 0, stream>>>(z2, W3, b3, z3, st + 1536);
  finalize_kernel<<<1, 128, 0, stream>>>(st + 1536, g3, be3, st + 3328, 128);

  bn_transpose_kernel<<<1024, 256, 0, stream>>>(z3, st + 3328, (float*)d_out);
}

// Round 7
// 606.749 us; speedup vs baseline: 1.6563x; 1.0146x over previous
//
#include <hip/hip_runtime.h>

#define NYTOT 16384
#define NXP 4096
#define MTOT 65536   // B * NY
#define CYC 128
#define CXC 256
#define DIMC 384

typedef __attribute__((ext_vector_type(8))) _Float16 half8;
typedef __attribute__((ext_vector_type(4))) _Float16 half4;
typedef __attribute__((ext_vector_type(4))) float floatx4;
typedef __attribute__((ext_vector_type(2))) float floatx2;

using half_t = _Float16;

struct alignas(16) HF8 { half_t h[8]; };

__device__ __forceinline__ float fmed3(float a, float b, float c) {
  return __builtin_amdgcn_fmed3f(a, b, c);
}

// ---------------- K0: build xq[b][j] = {x0,x1,x2,sx} (ref-order sx) -------
__global__ __launch_bounds__(1024) void xq_prep(
    const float* __restrict__ x_points, float4* __restrict__ xq) {
#pragma clang fp contract(off)
  int j = blockIdx.x * 1024 + threadIdx.x;          // 0..16383
  int b = j >> 12, jj = j & 4095;
  const float* p = x_points + (size_t)b * NXP * 3 + 3 * jj;
  float x0 = p[0], x1 = p[1], x2 = p[2];
  float sx = (x0 * x0 + x1 * x1) + x2 * x2;         // ref order
  float4 v; v.x = x0; v.y = x1; v.z = x2; v.w = sx;
  xq[j] = v;
}

// ---------------- K1: 3-NN interpolation + concat -> A0 fp16 [M, 384] ----
// Distances mirror numpy BIT-EXACTLY: fp32, contract(off), left-assoc,
// d = (sy + sx) - 2*inner. 2 y-points packed per lane (float2 elementwise =
// scalar IEEE per component). Candidate stream is wave-uniform global reads
// (readfirstlane'd base) -> no LDS traffic in the scan. Two-phase: value-only
// med3 top-3 -> global t2 per y -> gated stable index recovery. All merges
// iterate segments in ascending-j order => lowest-index-wins ties preserved.
__global__ __launch_bounds__(1024, 4) void interp_kernel(
    const float* __restrict__ y_points, const float* __restrict__ y_feats,
    const float* __restrict__ x_feats, const float4* __restrict__ xq,
    half_t* __restrict__ A0) {
#pragma clang fp contract(off)
  __shared__ float pd[8][256][3];         // 24 KB partial dists
  __shared__ int   pi[8][256][3];         // 24 KB partial idx
  __shared__ float t2s[256];              // 1 KB global 3rd-smallest
  __shared__ float sw[3][256];            // 3 KB final weights
  __shared__ int   si[3][256];            // 3 KB final idx
  const int b = blockIdx.x >> 6;
  const int chunk = blockIdx.x & 63;
  const int t = threadIdx.x;
  const int lane = t & 63;
  const int wid = t >> 6;
  const int seg = wid & 7;                // 8 segments x 512 candidates
  const int yhalf = wid >> 3;             // 2 y-halves x 128
  const int yloc = yhalf * 128 + (lane << 1);   // my 2 y's: yloc, yloc+1

  // y coords for the pair (rows are consecutive)
  const float* yp = y_points + ((size_t)b * NYTOT + chunk * 256 + yloc) * 3;
  floatx2 Y0 = {yp[0], yp[3]};
  floatx2 Y1 = {yp[1], yp[4]};
  floatx2 Y2 = {yp[2], yp[5]};
  floatx2 SY = (Y0 * Y0 + Y1 * Y1) + Y2 * Y2;     // ref order per element

  const float4* xqs = xq + (size_t)b * NXP;
  const int jb = __builtin_amdgcn_readfirstlane(seg * 512);

  // ---- phase 1: value-only top-3 per (seg, y) via med3/min ----
  floatx2 D0 = {1e30f, 1e30f}, D1 = D0, D2 = D0;
#pragma unroll 8
  for (int jj = 0; jj < 512; ++jj) {
    float4 p = xqs[jb + jj];                        // wave-uniform load
    floatx2 inner = (Y0 * p.x + Y1 * p.y) + Y2 * p.z;
    floatx2 d = (SY + p.w) - 2.0f * inner;
    D2.x = fmed3(d.x, D1.x, D2.x);  D2.y = fmed3(d.y, D1.y, D2.y);
    D1.x = fmed3(d.x, D0.x, D1.x);  D1.y = fmed3(d.y, D0.y, D1.y);
    D0.x = fminf(d.x, D0.x);        D0.y = fminf(d.y, D0.y);
  }
  pd[seg][yloc][0] = D0.x; pd[seg][yloc][1] = D1.x; pd[seg][yloc][2] = D2.x;
  pd[seg][yloc + 1][0] = D0.y; pd[seg][yloc + 1][1] = D1.y; pd[seg][yloc + 1][2] = D2.y;
  __syncthreads();

  // global 3rd-smallest per y
  if (t < 256) {
    float m0 = 1e30f, m1 = 1e30f, m2 = 1e30f;
#pragma unroll
    for (int s = 0; s < 8; ++s)
#pragma unroll
      for (int c = 0; c < 3; ++c) {
        float v = pd[s][t][c];
        m2 = fmed3(v, m1, m2);
        m1 = fmed3(v, m0, m1);
        m0 = fminf(v, m0);
      }
    t2s[t] = m2;
  }
  __syncthreads();

  // ---- phase 2: gated stable index recovery ----
  const float t2a = t2s[yloc], t2b = t2s[yloc + 1];
  const float tmax = fmaxf(t2a, t2b);
  float e0a = 1e30f, e1a = 1e30f, e2a = 1e30f; int k0a = 0, k1a = 0, k2a = 0;
  float e0b = 1e30f, e1b = 1e30f, e2b = 1e30f; int k0b = 0, k1b = 0, k2b = 0;
#pragma unroll 4
  for (int jj = 0; jj < 512; ++jj) {
    float4 p = xqs[jb + jj];
    floatx2 inner = (Y0 * p.x + Y1 * p.y) + Y2 * p.z;
    floatx2 d = (SY + p.w) - 2.0f * inner;
    if (fminf(d.x, d.y) <= tmax) {                  // ~9% of wave-iters
      int j = jb + jj;
      {
        float dv = d.x;
        bool l0 = dv < e0a, l1 = dv < e1a, l2 = dv < e2a;
        e2a = l1 ? e1a : (l2 ? dv : e2a);  k2a = l1 ? k1a : (l2 ? j : k2a);
        e1a = l0 ? e0a : (l1 ? dv : e1a);  k1a = l0 ? k0a : (l1 ? j : k1a);
        e0a = l0 ? dv : e0a;               k0a = l0 ? j : k0a;
      }
      {
        float dv = d.y;
        bool l0 = dv < e0b, l1 = dv < e1b, l2 = dv < e2b;
        e2b = l1 ? e1b : (l2 ? dv : e2b);  k2b = l1 ? k1b : (l2 ? j : k2b);
        e1b = l0 ? e0b : (l1 ? dv : e1b);  k1b = l0 ? k0b : (l1 ? j : k1b);
        e0b = l0 ? dv : e0b;               k0b = l0 ? j : k0b;
      }
    }
  }
  pd[seg][yloc][0] = e0a; pd[seg][yloc][1] = e1a; pd[seg][yloc][2] = e2a;
  pi[seg][yloc][0] = k0a; pi[seg][yloc][1] = k1a; pi[seg][yloc][2] = k2a;
  pd[seg][yloc + 1][0] = e0b; pd[seg][yloc + 1][1] = e1b; pd[seg][yloc + 1][2] = e2b;
  pi[seg][yloc + 1][0] = k0b; pi[seg][yloc + 1][1] = k1b; pi[seg][yloc + 1][2] = k2b;
  __syncthreads();

  // 24-way stable merge (seg-ascending) + weights
  if (t < 256) {
    float f0 = 1e30f, f1 = 1e30f, f2 = 1e30f;
    int m0i = 0, m1i = 0, m2i = 0;
#pragma unroll
    for (int s = 0; s < 8; ++s)
#pragma unroll
      for (int c = 0; c < 3; ++c) {
        float d = pd[s][t][c]; int j = pi[s][t][c];
        bool l0 = d < f0, l1 = d < f1, l2 = d < f2;
        f2 = l1 ? f1 : (l2 ? d : f2);  m2i = l1 ? m1i : (l2 ? j : m2i);
        f1 = l0 ? f0 : (l1 ? d : f1);  m1i = l0 ? m0i : (l1 ? j : m1i);
        f0 = l0 ? d : f0;              m0i = l0 ? j : m0i;
      }
    float w0 = 1.0f / (f0 + 1e-8f), w1 = 1.0f / (f1 + 1e-8f), w2 = 1.0f / (f2 + 1e-8f);
    float ws = (w0 + w1) + w2;
    sw[0][t] = w0 / ws; sw[1][t] = w1 / ws; sw[2][t] = w2 / ws;
    si[0][t] = m0i; si[1][t] = m1i; si[2][t] = m2i;
  }
  __syncthreads();

  // ---- gather: vectorized float4 rows (row index wave-uniform -> 1KB loads)
  const floatx4* xf4 = (const floatx4*)(x_feats + (size_t)b * NXP * CXC);
  const floatx4* yf4 = (const floatx4*)(y_feats + ((size_t)b * NYTOT + chunk * 256) * CYC);
  half_t* fb = A0 + ((size_t)b * NYTOT + chunk * 256) * DIMC;
  {
    const int q = t & 63;           // float4 index within 256-ch row
    const int ysub = t >> 6;        // 16 y-groups
    for (int y2 = ysub; y2 < 256; y2 += 16) {
      int j0 = si[0][y2], j1 = si[1][y2], j2 = si[2][y2];
      float a0 = sw[0][y2], a1 = sw[1][y2], a2 = sw[2][y2];
      floatx4 v0 = xf4[(size_t)j0 * 64 + q];
      floatx4 v1 = xf4[(size_t)j1 * 64 + q];
      floatx4 v2 = xf4[(size_t)j2 * 64 + q];
      half4 h;
#pragma unroll
      for (int e = 0; e < 4; ++e)
        h[e] = (half_t)fmaf(v2[e], a2, fmaf(v1[e], a1, v0[e] * a0));
      *(half4*)&fb[(size_t)y2 * DIMC + CYC + q * 4] = h;
    }
  }
  {
    const int q2 = t & 31;          // float4 index within 128-ch row
    const int ysub2 = t >> 5;       // 32 y-groups
    for (int y2 = ysub2; y2 < 256; y2 += 32) {
      floatx4 v = yf4[(size_t)y2 * 32 + q2];
      half4 h;
#pragma unroll
      for (int e = 0; e < 4; ++e) h[e] = (half_t)v[e];
      *(half4*)&fb[(size_t)y2 * DIMC + q2 * 4] = h;
    }
  }
}

// ---------------- GEMM: C[M,O] = A[M,K](fp16) * W[O,K](fp32)^T + bias ----
// 128x128 tile, BK=64, 4 waves (2x2), mfma_f32_16x16x32_f16.
// A staged via global_load_lds (16B); W converted fp32->fp16 via VGPR+ds_write.
// Fused BN stats: per-channel sum/sumsq of z reduced in-wave, atomicAdd.
template<int K, int O>
__global__ __launch_bounds__(256) void gemm_f16(
    const half_t* __restrict__ A, const float* __restrict__ W,
    const float* __restrict__ bias, half_t* __restrict__ C,
    float* __restrict__ sums) {
  __shared__ __align__(16) short As[8][2][512];   // [m_sub][k_sub][lane*8+e]
  __shared__ __align__(16) short Bs[8][2][512];
  const int m0 = blockIdx.x * 128;
  const int n0 = blockIdx.y * 128;
  const int tid = threadIdx.x;
  const int lane = tid & 63;
  const int wid = tid >> 6;
  const int wm = wid >> 1, wn = wid & 1;
  const int lm = lane & 15;            // row within 16-subtile
  const int lk = (lane >> 4) * 8;      // k offset within 32
  const int r = tid & 127;             // W-staging: n-row within tile
  const int hh = tid >> 7;             // W-staging: k-half selector
  floatx4 acc[4][4] = {};

  for (int k0 = 0; k0 < K; k0 += 64) {
    __syncthreads();
    // A: 16 chunks of 1 KB via async global->LDS (A already fp16)
#pragma unroll
    for (int c = 0; c < 4; ++c) {
      int id = wid * 4 + c;            // 0..15
      int sub = id >> 1;
      int ks = id & 1;
      const half_t* src = A + (size_t)(m0 + sub * 16 + lm) * K + (k0 + ks * 32 + lk);
      __builtin_amdgcn_global_load_lds(
          (const __attribute__((address_space(1))) void*)src,
          (__attribute__((address_space(3))) void*)&As[sub][ks][0], 16, 0, 0);
    }
    // W: fp32 -> fp16 convert-staging into fragment-ordered LDS
#pragma unroll
    for (int ks = 0; ks < 2; ++ks) {
#pragma unroll
      for (int g = 0; g < 4; ++g) {
        int kw = hh * 16 + g * 4;
        const floatx4 wv = *(const floatx4*)&W[(size_t)(n0 + r) * K + k0 + ks * 32 + kw];
        half4 hv;
        hv[0] = (half_t)wv[0]; hv[1] = (half_t)wv[1];
        hv[2] = (half_t)wv[2]; hv[3] = (half_t)wv[3];
        *(half4*)&Bs[r >> 4][ks][((kw >> 3) * 16 + (r & 15)) * 8 + (kw & 7)] = hv;
      }
    }
    __syncthreads();
#pragma unroll
    for (int ks = 0; ks < 2; ++ks) {
      half8 af[4], bfm[4];
#pragma unroll
      for (int i = 0; i < 4; ++i) af[i] = *(const half8*)&As[wm * 4 + i][ks][lane * 8];
#pragma unroll
      for (int j = 0; j < 4; ++j) bfm[j] = *(const half8*)&Bs[wn * 4 + j][ks][lane * 8];
#pragma unroll
      for (int i = 0; i < 4; ++i)
#pragma unroll
        for (int j = 0; j < 4; ++j)
          acc[i][j] = __builtin_amdgcn_mfma_f32_16x16x32_f16(af[i], bfm[j], acc[i][j], 0, 0, 0);
    }
  }

  // epilogue: C/D layout col=lane&15, row=(lane>>4)*4+r; fused BN stats
#pragma unroll
  for (int j = 0; j < 4; ++j) {
    int nn = n0 + wn * 64 + j * 16 + lm;
    float bv = bias[nn];
    float psum = 0.f, psq = 0.f;
#pragma unroll
    for (int i = 0; i < 4; ++i) {
      int mr = m0 + wm * 64 + i * 16 + (lane >> 4) * 4;
#pragma unroll
      for (int rr = 0; rr < 4; ++rr) {
        float z = acc[i][j][rr] + bv;
        C[(size_t)(mr + rr) * O + nn] = (half_t)z;
        psum += z; psq += z * z;
      }
    }
    // reduce the 4 lane-groups holding channel nn (lanes lm, lm+16, lm+32, lm+48)
    psum += __shfl_xor(psum, 16, 64); psq += __shfl_xor(psq, 16, 64);
    psum += __shfl_xor(psum, 32, 64); psq += __shfl_xor(psq, 32, 64);
    if ((lane >> 4) == 0) {
      atomicAdd(&sums[nn], psum);
      atomicAdd(&sums[O + nn], psq);
    }
  }
}

// ---------------- finalize BN scale/shift ----------
__global__ void finalize_kernel(const float* __restrict__ sums, const float* __restrict__ g,
                                const float* __restrict__ be, float* __restrict__ ss, int O) {
  int c = threadIdx.x;
  if (c < O) {
    const float invN = 1.0f / 65536.0f;
    float mean = sums[c] * invN;
    float var = sums[O + c] * invN - mean * mean;
    float sc = g[c] / sqrtf(var + 1e-5f);
    float sh = be[c] - mean * sc;
    if (!isfinite(sc) || !isfinite(sh)) { sc = 1.0f; sh = 0.0f; }
    ss[c] = sc;
    ss[O + c] = sh;
  }
}

// ---------------- in-place BN + ReLU (O is power of two) ----------------
__global__ __launch_bounds__(256) void bnrelu_kernel(
    half_t* __restrict__ Z, const float* __restrict__ ss, int O) {
  size_t i = (size_t)blockIdx.x * 256 + threadIdx.x;
  int c0 = (int)((i * 8) & (size_t)(O - 1));
  HF8 v = ((const HF8*)Z)[i];
#pragma unroll
  for (int e = 0; e < 8; ++e) {
    int cc = c0 + e;
    float f = fmaxf((float)v.h[e] * ss[cc] + ss[O + cc], 0.f);
    v.h[e] = (half_t)f;
  }
  ((HF8*)Z)[i] = v;
}

// ---------------- layer3 BN + ReLU + transpose to [B, C, N] fp32 --------
__global__ __launch_bounds__(256) void bn_transpose_kernel(
    const half_t* __restrict__ Z3, const float* __restrict__ ss, float* __restrict__ out) {
  __shared__ float tile[64][129];
  const int r0 = blockIdx.x * 64;
  const int b = r0 >> 14;
  const int n0 = r0 & (NYTOT - 1);
  const int t = threadIdx.x;
  const int cl = t & 127, rl = t >> 7;      // 2 rows per pass
  for (int p = 0; p < 32; ++p) {
    int rr = p * 2 + rl;
    float v = (float)Z3[(size_t)(r0 + rr) * 128 + cl];
    tile[rr][cl] = fmaxf(v * ss[cl] + ss[128 + cl], 0.f);
  }
  __syncthreads();
  const int nl = t & 63, cj = t >> 6;       // 4 channels per pass
  for (int p = 0; p < 32; ++p) {
    int c = p * 4 + cj;
    out[(size_t)b * 128 * NYTOT + (size_t)c * NYTOT + n0 + nl] = tile[nl][c];
  }
}

extern "C" void kernel_launch(void* const* d_in, const int* in_sizes, int n_in,
                              void* d_out, int out_size, void* d_ws, size_t ws_size,
                              hipStream_t stream) {
  const float* y_points = (const float*)d_in[0];
  const float* y_feats  = (const float*)d_in[1];
  const float* x_points = (const float*)d_in[2];
  const float* x_feats  = (const float*)d_in[3];
  const float* W1 = (const float*)d_in[4];  const float* b1 = (const float*)d_in[5];
  const float* g1 = (const float*)d_in[6];  const float* be1 = (const float*)d_in[7];
  const float* W2 = (const float*)d_in[8];  const float* b2 = (const float*)d_in[9];
  const float* g2 = (const float*)d_in[10]; const float* be2 = (const float*)d_in[11];
  const float* W3 = (const float*)d_in[12]; const float* b3 = (const float*)d_in[13];
  const float* g3 = (const float*)d_in[14]; const float* be3 = (const float*)d_in[15];

  // workspace layout (peak 117,447,680 B == 112.02 MiB, proven to fit):
  //   [0, 50.33MB)        : A0 fp16 [M,384]  (later aliased by z2)
  //   [50.33MB, 117.44MB) : z1 fp16 [M,512]  (xq table lives here pre-gemm1,
  //                         later aliased by z3)
  //   [117.44MB, +7KB)    : BN stats
  char* ws = (char*)d_ws;
  half_t* A0 = (half_t*)ws;                      // 65536*384*2 = 50,331,648
  half_t* z1 = (half_t*)(ws + 50331648);         // 65536*512*2 = 67,108,864
  half_t* z2 = (half_t*)ws;                      // alias A0 (dead after gemm1)
  half_t* z3 = (half_t*)(ws + 50331648);         // alias z1 (dead after gemm2)
  float4* xq = (float4*)(ws + 50331648);         // alias z1 head (dead before gemm1)
  float* st = (float*)(ws + 117440512);
  // st floats: sum1/sq1 @0 (1024), sum2/sq2 @1024 (512), sum3/sq3 @1536 (256),
  //            ss1 @1792 (1024), ss2 @2816 (512), ss3 @3328 (256)
  hipMemsetAsync(st, 0, 1792 * sizeof(float), stream);

  xq_prep<<<16, 1024, 0, stream>>>(x_points, xq);
  interp_kernel<<<256, 1024, 0, stream>>>(y_points, y_feats, x_feats, xq, A0);

  gemm_f16<384, 512><<<dim3(512, 4), 256, 0, stream>>>(A0, W1, b1, z1, st + 0);
  finalize_kernel<<<1, 512, 0, stream>>>(st + 0, g1, be1, st + 1792, 512);
  bnrelu_kernel<<<16384, 256, 0, stream>>>(z1, st + 1792, 512);

  gemm_f16<512, 256><<<dim3(512, 2), 256, 0, stream>>>(z1, W2, b2, z2, st + 1024);
  finalize_kernel<<<1, 256, 0, stream>>>(st + 1024, g2, be2, st + 2816, 256);
  bnrelu_kernel<<<8192, 256, 0, stream>>>(z2, st + 2816, 256);

  gemm_f16<256, 128><<<dim3(512, 1), 256, 0, stream>>>(z2, W3, b3, z3, st + 1536);
  finalize_kernel<<<1, 128, 0, stream>>>(st + 1536, g3, be3, st + 3328, 128);

  bn_transpose_kernel<<<1024, 256, 0, stream>>>(z3, st + 3328, (float*)d_out);
}